// Round 1
// baseline (174.430 us; speedup 1.0000x reference)
//
#include <hip/hip_runtime.h>
#include <hip/hip_bf16.h>

// Phase 1: per-row sum of squared diffs -> per_sample[row] = mean
// One block (256 threads) per row; 8192 cols = 2048 float4 per row.
__global__ __launch_bounds__(256) void row_mse_kernel(const float4* __restrict__ o4,
                                                      const float4* __restrict__ y4,
                                                      float* __restrict__ per) {
    const int row = blockIdx.x;
    const int C4 = 8192 / 4;  // 2048
    const size_t base = (size_t)row * C4;

    float acc = 0.0f;
    for (int i = threadIdx.x; i < C4; i += 256) {
        float4 a = o4[base + i];
        float4 b = y4[base + i];
        float d0 = a.x - b.x;
        float d1 = a.y - b.y;
        float d2 = a.z - b.z;
        float d3 = a.w - b.w;
        acc += d0 * d0 + d1 * d1 + d2 * d2 + d3 * d3;
    }

    // wave (64-lane) shuffle reduce
    for (int off = 32; off > 0; off >>= 1) acc += __shfl_down(acc, off, 64);

    __shared__ float wsum[4];
    const int lane = threadIdx.x & 63;
    const int wid = threadIdx.x >> 6;
    if (lane == 0) wsum[wid] = acc;
    __syncthreads();
    if (threadIdx.x == 0) {
        float t = wsum[0] + wsum[1] + wsum[2] + wsum[3];
        per[row] = t * (1.0f / 8192.0f);
    }
}

// Phase 2: single block: bitonic-sort the 8192 per-row values in LDS
// (ascending), sum the top 4096 (indices 4096..8191), write scalar.
__global__ __launch_bounds__(1024) void topk_sum_kernel(const float* __restrict__ per,
                                                        float* __restrict__ out) {
    __shared__ float s[8192];
    const int tid = threadIdx.x;

    #pragma unroll
    for (int p = 0; p < 8; ++p) s[tid + p * 1024] = per[tid + p * 1024];
    __syncthreads();

    // full bitonic sort, ascending
    for (int k = 2; k <= 8192; k <<= 1) {
        for (int j = k >> 1; j > 0; j >>= 1) {
            #pragma unroll
            for (int p = 0; p < 8; ++p) {
                int i = tid + p * 1024;
                int ixj = i ^ j;
                if (ixj > i) {
                    bool up = ((i & k) == 0);
                    float a = s[i];
                    float b = s[ixj];
                    if ((a > b) == up) { s[i] = b; s[ixj] = a; }
                }
            }
            __syncthreads();
        }
    }

    // sum top half: indices 4096..8191
    float acc = 0.0f;
    #pragma unroll
    for (int p = 4; p < 8; ++p) acc += s[tid + p * 1024];
    __syncthreads();
    s[tid] = acc;
    __syncthreads();
    for (int stride = 512; stride > 0; stride >>= 1) {
        if (tid < stride) s[tid] += s[tid + stride];
        __syncthreads();
    }
    if (tid == 0) out[0] = s[0];
}

extern "C" void kernel_launch(void* const* d_in, const int* in_sizes, int n_in,
                              void* d_out, int out_size, void* d_ws, size_t ws_size,
                              hipStream_t stream) {
    const float* o = (const float*)d_in[0];
    const float* y = (const float*)d_in[1];
    float* per = (float*)d_ws;       // 8192 floats = 32 KB scratch
    float* out = (float*)d_out;      // 1 float

    row_mse_kernel<<<8192, 256, 0, stream>>>((const float4*)o, (const float4*)y, per);
    topk_sum_kernel<<<1, 1024, 0, stream>>>(per, out);
}

// Round 2
// 112.813 us; speedup vs baseline: 1.5462x; 1.5462x over previous
//
#include <hip/hip_runtime.h>
#include <hip/hip_bf16.h>

// Phase 1: per-row sum of squared diffs -> per_sample[row] = mean.
// One block (256 threads) per row; 8192 cols = 2048 float4 per row.
__global__ __launch_bounds__(256) void row_mse_kernel(const float4* __restrict__ o4,
                                                      const float4* __restrict__ y4,
                                                      float* __restrict__ per) {
    const int row = blockIdx.x;
    const int C4 = 8192 / 4;  // 2048
    const size_t base = (size_t)row * C4;

    float acc = 0.0f;
    for (int i = threadIdx.x; i < C4; i += 256) {
        float4 a = o4[base + i];
        float4 b = y4[base + i];
        float d0 = a.x - b.x;
        float d1 = a.y - b.y;
        float d2 = a.z - b.z;
        float d3 = a.w - b.w;
        acc += d0 * d0 + d1 * d1 + d2 * d2 + d3 * d3;
    }

    // wave (64-lane) shuffle reduce
    for (int off = 32; off > 0; off >>= 1) acc += __shfl_down(acc, off, 64);

    __shared__ float wsum[4];
    const int lane = threadIdx.x & 63;
    const int wid = threadIdx.x >> 6;
    if (lane == 0) wsum[wid] = acc;
    __syncthreads();
    if (threadIdx.x == 0) {
        float t = wsum[0] + wsum[1] + wsum[2] + wsum[3];
        per[row] = t * (1.0f / 8192.0f);
    }
}

// Phase 2: single 1024-thread block. Radix-select the k-th largest (k=4096)
// of the 8192 per-row values via MSB-first 8-bit histogram passes, then
// sum = sum(v where key > K) + kk * value(K).  Exact under ties.
__global__ __launch_bounds__(1024) void topk_sum_kernel(const float* __restrict__ per,
                                                        float* __restrict__ out) {
    const int tid = threadIdx.x;

    // Load 8 values/thread into registers; build order-preserving uint keys.
    float v[8];
    unsigned key[8];
    #pragma unroll
    for (int p = 0; p < 8; ++p) {
        float f = per[tid + p * 1024];
        v[p] = f;
        unsigned u = __float_as_uint(f);
        key[p] = (u & 0x80000000u) ? ~u : (u | 0x80000000u);
    }

    __shared__ unsigned hist[256];
    __shared__ unsigned bc_prefix;
    __shared__ unsigned bc_k;

    unsigned prefix = 0;   // selected high bits (in position)
    unsigned kk = 4096;    // how many still to select among prefix-matching keys

    for (int shift = 24; shift >= 0; shift -= 8) {
        if (tid < 256) hist[tid] = 0;
        __syncthreads();

        const unsigned mask_hi = (shift == 24) ? 0u : (0xFFFFFFFFu << (shift + 8));
        #pragma unroll
        for (int p = 0; p < 8; ++p) {
            if ((key[p] & mask_hi) == prefix) {
                atomicAdd(&hist[(key[p] >> shift) & 255u], 1u);
            }
        }
        __syncthreads();

        if (tid == 0) {
            unsigned cum = 0;
            for (int b = 255; b >= 0; --b) {
                unsigned c = hist[b];
                if (cum + c >= kk) {
                    bc_prefix = prefix | ((unsigned)b << shift);
                    bc_k = kk - cum;
                    break;
                }
                cum += c;
            }
        }
        __syncthreads();
        prefix = bc_prefix;
        kk = bc_k;
    }

    // Sum of values strictly greater than threshold key K = prefix.
    const unsigned K = prefix;
    float s = 0.0f;
    #pragma unroll
    for (int p = 0; p < 8; ++p) {
        if (key[p] > K) s += v[p];
    }
    for (int off = 32; off > 0; off >>= 1) s += __shfl_down(s, off, 64);

    __shared__ float wsums[16];
    const int lane = tid & 63;
    const int wid = tid >> 6;
    if (lane == 0) wsums[wid] = s;
    __syncthreads();
    if (tid == 0) {
        float t = 0.0f;
        #pragma unroll
        for (int i = 0; i < 16; ++i) t += wsums[i];
        // invert key transform to recover threshold value
        unsigned u = (K & 0x80000000u) ? (K & 0x7FFFFFFFu) : ~K;
        float valK = __uint_as_float(u);
        out[0] = t + (float)kk * valK;
    }
}

extern "C" void kernel_launch(void* const* d_in, const int* in_sizes, int n_in,
                              void* d_out, int out_size, void* d_ws, size_t ws_size,
                              hipStream_t stream) {
    const float* o = (const float*)d_in[0];
    const float* y = (const float*)d_in[1];
    float* per = (float*)d_ws;       // 8192 floats = 32 KB scratch
    float* out = (float*)d_out;      // 1 float

    row_mse_kernel<<<8192, 256, 0, stream>>>((const float4*)o, (const float4*)y, per);
    topk_sum_kernel<<<1, 1024, 0, stream>>>(per, out);
}

// Round 3
// 101.435 us; speedup vs baseline: 1.7196x; 1.1122x over previous
//
#include <hip/hip_runtime.h>
#include <hip/hip_bf16.h>

#define K_SEL 4096

// Phase 1: per-row mean of squared diffs. One 256-thread block per row.
// All 16 float4 loads hoisted into registers => 256 B in flight per thread.
__global__ __launch_bounds__(256) void row_mse_kernel(const float4* __restrict__ o4,
                                                      const float4* __restrict__ y4,
                                                      float* __restrict__ per) {
    const int row = blockIdx.x;
    const int tid = threadIdx.x;
    const size_t base = (size_t)row * 2048;  // 8192 cols / 4

    float4 a[8], b[8];
    #pragma unroll
    for (int p = 0; p < 8; ++p) a[p] = o4[base + tid + p * 256];
    #pragma unroll
    for (int p = 0; p < 8; ++p) b[p] = y4[base + tid + p * 256];

    float acc = 0.0f;
    #pragma unroll
    for (int p = 0; p < 8; ++p) {
        float d0 = a[p].x - b[p].x;
        float d1 = a[p].y - b[p].y;
        float d2 = a[p].z - b[p].z;
        float d3 = a[p].w - b[p].w;
        acc += d0 * d0 + d1 * d1 + d2 * d2 + d3 * d3;
    }

    for (int off = 32; off > 0; off >>= 1) acc += __shfl_down(acc, off, 64);

    __shared__ float wsum[4];
    const int lane = tid & 63;
    const int wid = tid >> 6;
    if (lane == 0) wsum[wid] = acc;
    __syncthreads();
    if (tid == 0) {
        per[row] = (wsum[0] + wsum[1] + wsum[2] + wsum[3]) * (1.0f / 8192.0f);
    }
}

// Phase 2: single 1024-thread block. Linear-bin select of the k-th largest
// (k=4096) of 8192 values, then S = sum(v > T) + (k - cnt(v > T)) * T.
__global__ __launch_bounds__(1024) void topk_sum_kernel(const float* __restrict__ per,
                                                        float* __restrict__ out) {
    const int tid = threadIdx.x;
    const int lane = tid & 63;
    const int wid = tid >> 6;

    float v[8];
    #pragma unroll
    for (int p = 0; p < 8; ++p) v[p] = per[tid + p * 1024];

    // ---- global min/max ----
    float mn = v[0], mx = v[0];
    #pragma unroll
    for (int p = 1; p < 8; ++p) { mn = fminf(mn, v[p]); mx = fmaxf(mx, v[p]); }
    for (int off = 32; off > 0; off >>= 1) {
        mn = fminf(mn, __shfl_down(mn, off, 64));
        mx = fmaxf(mx, __shfl_down(mx, off, 64));
    }
    __shared__ float wmn[16], wmx[16];
    __shared__ float s_lo, s_hi, s_T;
    __shared__ int s_bin, s_kkb;
    if (lane == 0) { wmn[wid] = mn; wmx[wid] = mx; }
    __syncthreads();
    if (tid == 0) {
        float a = wmn[0], b = wmx[0];
        for (int i = 1; i < 16; ++i) { a = fminf(a, wmn[i]); b = fmaxf(b, wmx[i]); }
        s_lo = a; s_hi = b;
    }
    __syncthreads();
    const float lo = s_lo, hi = s_hi;

    float T;
    __shared__ unsigned hist[4096];
    __shared__ float cand[1024];
    __shared__ unsigned ccnt;

    if (hi <= lo) {
        T = lo;  // all values equal
    } else {
        const float scale = 4096.0f / (hi - lo);
        const float w = (hi - lo) * (1.0f / 4096.0f);

        // ---- histogram ----
        #pragma unroll
        for (int i = 0; i < 4; ++i) hist[tid + i * 1024] = 0;
        __syncthreads();
        #pragma unroll
        for (int p = 0; p < 8; ++p) {
            int idx = (int)((v[p] - lo) * scale);
            idx = idx < 0 ? 0 : (idx > 4095 ? 4095 : idx);
            atomicAdd(&hist[idx], 1u);
        }
        __syncthreads();

        // ---- suffix scan (descending bins): thread tid owns group g = 1023-tid ----
        const int g = 1023 - tid;
        unsigned c = hist[4 * g] + hist[4 * g + 1] + hist[4 * g + 2] + hist[4 * g + 3];
        unsigned x = c;
        for (int off = 1; off < 64; off <<= 1) {
            unsigned t2 = __shfl_up(x, off, 64);
            if (lane >= off) x += t2;
        }
        __shared__ unsigned wtot[16];
        if (lane == 63) wtot[wid] = x;
        __syncthreads();
        unsigned basec = 0;
        for (int i = 0; i < wid; ++i) basec += wtot[i];
        const unsigned incl = basec + x;  // count of values in bins >= 4g

        if (incl >= K_SEL && (incl - c) < K_SEL) {
            // crossing group: walk its 4 bins from high to low
            unsigned cum = incl - c;
            for (int b = 4 * g + 3; b >= 4 * g; --b) {
                unsigned hb = hist[b];
                if (cum + hb >= K_SEL) {
                    s_bin = b;
                    s_kkb = (int)(K_SEL - cum);  // rank within the bin (1-based)
                    break;
                }
                cum += hb;
            }
        }
        __syncthreads();
        const int bin = s_bin;
        const int kkb = s_kkb;

        // ---- collect candidates in threshold bin ----
        if (tid == 0) ccnt = 0;
        __syncthreads();
        #pragma unroll
        for (int p = 0; p < 8; ++p) {
            int idx = (int)((v[p] - lo) * scale);
            idx = idx < 0 ? 0 : (idx > 4095 ? 4095 : idx);
            if (idx == bin) {
                unsigned a = atomicAdd(&ccnt, 1u);
                if (a < 1024) cand[a] = v[p];
            }
        }
        __syncthreads();

        if (tid == 0) {
            int n = (int)(ccnt < 1024u ? ccnt : 1024u);
            float thr;
            if (n > 0 && n <= 64 && kkb <= n) {
                // exact: kkb-th largest among candidates (repeated max extraction)
                thr = cand[0];
                for (int e = 0; e < kkb; ++e) {
                    float best = -1e30f; int bi = 0;
                    for (int i = 0; i < n; ++i) {
                        float cc = cand[i];
                        if (cc > best) { best = cc; bi = i; }
                    }
                    cand[bi] = -1e30f;
                    thr = best;
                }
            } else {
                // approximate (self-correcting final formula): bin upper edge
                thr = lo + (float)(bin + 1) * w;
            }
            s_T = thr;
        }
        __syncthreads();
        T = s_T;
    }

    // ---- final: S = sum(v > T) + (k - cnt(v > T)) * T ----
    float ssum = 0.0f;
    float cgt = 0.0f;
    #pragma unroll
    for (int p = 0; p < 8; ++p) {
        if (v[p] > T) { ssum += v[p]; cgt += 1.0f; }
    }
    for (int off = 32; off > 0; off >>= 1) {
        ssum += __shfl_down(ssum, off, 64);
        cgt += __shfl_down(cgt, off, 64);
    }
    __shared__ float wss[16], wcg[16];
    if (lane == 0) { wss[wid] = ssum; wcg[wid] = cgt; }
    __syncthreads();
    if (tid == 0) {
        float ts = 0.0f, tc = 0.0f;
        for (int i = 0; i < 16; ++i) { ts += wss[i]; tc += wcg[i]; }
        out[0] = ts + ((float)K_SEL - tc) * T;
    }
}

extern "C" void kernel_launch(void* const* d_in, const int* in_sizes, int n_in,
                              void* d_out, int out_size, void* d_ws, size_t ws_size,
                              hipStream_t stream) {
    const float* o = (const float*)d_in[0];
    const float* y = (const float*)d_in[1];
    float* per = (float*)d_ws;       // 8192 floats = 32 KB scratch
    float* out = (float*)d_out;      // 1 float

    row_mse_kernel<<<8192, 256, 0, stream>>>((const float4*)o, (const float4*)y, per);
    topk_sum_kernel<<<1, 1024, 0, stream>>>(per, out);
}